// Round 10
// baseline (463.642 us; speedup 1.0000x reference)
//
#include <hip/hip_runtime.h>
#include <hip/hip_cooperative_groups.h>
#include <hip/hip_bf16.h>
#include <math.h>

namespace cg = cooperative_groups;

// Problem dims
#define Bb 4
#define Sdim 2048
#define Ddim 512
#define Nn16 16
#define TOK 8192          // Bb*Sdim
#define NCh 64            // chunks along S
#define LCh 32            // steps per chunk

using bf16x8 = __attribute__((ext_vector_type(8))) __bf16;
using f32x4  = __attribute__((ext_vector_type(4))) float;

__device__ __forceinline__ unsigned short f2bf(float f) {
    unsigned int u = __float_as_uint(f);
    u += 0x7fffu + ((u >> 16) & 1u);
    return (unsigned short)(u >> 16);
}
__device__ __forceinline__ float bf2f(unsigned short h) {
    return __uint_as_float(((unsigned int)h) << 16);
}

// async global->LDS, 16B/lane; LDS base wave-uniform
#define GLD16(g, l) __builtin_amdgcn_global_load_lds( \
    (const __attribute__((address_space(1))) void*)(g), \
    (__attribute__((address_space(3))) void*)(l), 16, 0, 0)

__device__ __forceinline__ float softplus_f(float v) {
    return v > 20.f ? v : log1pf(__expf(v));
}

// ===========================================================================
// Shared device bodies (used by both fused and fallback paths)
// ===========================================================================

// one 32x32 transpose-cast job (job < 560) or one 32-row LN job (560..815)
__device__ __forceinline__ void prep_job(
    int job, int tid, char* smem,
    const float* x, const float* gamma, const float* beta,
    const float* Wp, const float* Wb, const float* Wdbc, const float* Wdt,
    ushort* xn, ushort* Wpt, ushort* Wbt, ushort* Wdbct, ushort* WdtT)
{
    if (job < 560) {
        float* tb = (float*)smem;
        int xx = tid & 31, yy0 = tid >> 5;
        const float* in; ushort* outT; int K, N, bx, by;
        if (job < 256)      { in = Wp;   outT = Wpt;   K = 512; N = 512; bx = (job & 15) * 32; by = (job >> 4) * 32; }
        else if (job < 512) { int t = job - 256; in = Wb; outT = Wbt; K = 512; N = 512; bx = (t & 15) * 32; by = (t >> 4) * 32; }
        else if (job < 544) { int t = job - 512; in = Wdbc; outT = Wdbct; K = 512; N = 64; bx = (t & 1) * 32; by = (t >> 1) * 32; }
        else                { int t = job - 544; in = Wdt; outT = WdtT; K = 32; N = 512; bx = t * 32; by = 0; }
        #pragma unroll
        for (int yy = yy0; yy < 32; yy += 8)
            tb[yy * 33 + xx] = in[(size_t)(by + yy) * N + bx + xx];
        __syncthreads();
        #pragma unroll
        for (int yy = yy0; yy < 32; yy += 8)
            outT[(size_t)(bx + yy) * K + by + xx] = f2bf(tb[xx * 33 + yy]);
    } else {
        int bid = job - 560;                 // 0..255
        int w = tid >> 6, lane = tid & 63;
        const float4* g4 = (const float4*)gamma;
        const float4* b4 = (const float4*)beta;
        float4 g0 = g4[lane], g1 = g4[lane + 64];
        float4 be0 = b4[lane], be1 = b4[lane + 64];
        for (int rr = 0; rr < 8; ++rr) {
            int row = bid * 32 + w * 8 + rr;
            const float4* xr = (const float4*)(x + (size_t)row * Ddim);
            float4 v0 = xr[lane];
            float4 v1 = xr[lane + 64];
            float s = v0.x + v0.y + v0.z + v0.w + v1.x + v1.y + v1.z + v1.w;
            float q = v0.x*v0.x + v0.y*v0.y + v0.z*v0.z + v0.w*v0.w
                    + v1.x*v1.x + v1.y*v1.y + v1.z*v1.z + v1.w*v1.w;
            #pragma unroll
            for (int m = 1; m <= 32; m <<= 1) { s += __shfl_xor(s, m); q += __shfl_xor(q, m); }
            float mu = s * (1.0f / Ddim);
            float var = q * (1.0f / Ddim) - mu * mu;
            float rs = rsqrtf(var + 1e-5f);
            ushort4 u0, u1;
            u0.x = f2bf((v0.x - mu) * rs * g0.x + be0.x);
            u0.y = f2bf((v0.y - mu) * rs * g0.y + be0.y);
            u0.z = f2bf((v0.z - mu) * rs * g0.z + be0.z);
            u0.w = f2bf((v0.w - mu) * rs * g0.w + be0.w);
            u1.x = f2bf((v1.x - mu) * rs * g1.x + be1.x);
            u1.y = f2bf((v1.y - mu) * rs * g1.y + be1.y);
            u1.z = f2bf((v1.z - mu) * rs * g1.z + be1.z);
            u1.w = f2bf((v1.w - mu) * rs * g1.w + be1.w);
            *(ushort4*)(xn + (size_t)row * Ddim + lane * 4) = u0;
            *(ushort4*)(xn + (size_t)row * Ddim + 256 + lane * 4) = u1;
        }
    }
}

// one 64x64 GEMM tile, BK=64 XOR-swizzled (round-9-proven gemm64 body)
__device__ __forceinline__ void gemm64_tile(
    const ushort* A, const ushort* Bt, const float* bias, ushort* Cb,
    int bm, int bn, char* smem)
{
    ushort* As = (ushort*)smem;            // 8KB
    ushort* Bs = (ushort*)(smem + 8192);   // 8KB
    int tid = threadIdx.x, w = tid >> 6, lane = tid & 63;
    int quad = lane >> 4, l16 = lane & 15;
    int srow8 = lane >> 3;
    int scolx = ((lane & 7) ^ srow8) * 8;
    int cof0 = (quad ^ (l16 & 7)) * 8;
    int cof1 = ((4 + quad) ^ (l16 & 7)) * 8;
    f32x4 acc[4] = {};

    for (int k0 = 0; k0 < 512; k0 += 64) {
        __syncthreads();
        #pragma unroll
        for (int s = 0; s < 2; ++s) {
            int r = w * 16 + s * 8;
            GLD16(A  + (size_t)(bm + r + srow8) * 512 + k0 + scolx, &As[r * 64]);
            GLD16(Bt + (size_t)(bn + r + srow8) * 512 + k0 + scolx, &Bs[r * 64]);
        }
        __syncthreads();
        #pragma unroll
        for (int ks = 0; ks < 2; ++ks) {
            int cof = ks ? cof1 : cof0;
            bf16x8 bfr = *(const bf16x8*)(const void*)&Bs[(w * 16 + l16) * 64 + cof];
            #pragma unroll
            for (int i = 0; i < 4; ++i) {
                bf16x8 af = *(const bf16x8*)(const void*)&As[(16 * i + l16) * 64 + cof];
                acc[i] = __builtin_amdgcn_mfma_f32_16x16x32_bf16(af, bfr, acc[i], 0, 0, 0);
            }
        }
    }
    int col = bn + w * 16 + l16;
    float bv = bias[col];
    #pragma unroll
    for (int i = 0; i < 4; ++i) {
        int row = bm + 16 * i + quad * 4;
        #pragma unroll
        for (int r = 0; r < 4; ++r)
            Cb[(size_t)(row + r) * 512 + col] = f2bf(acc[i][r] + bv);
    }
    __syncthreads();   // LDS safe for next tile/phase
}

// fused dbc+delta for 32 token-rows (round-9-proven dbc_delta body)
__device__ __forceinline__ void dbc_delta_tile(
    const ushort* bwd, const ushort* Wdbct, const ushort* WdtT,
    const float* b_dt, float* BC, ushort* delta, int bm, char* smem)
{
    ushort* As   = (ushort*)smem;            // 4KB  [32][64]
    ushort* Bs   = (ushort*)(smem + 4096);   // 8KB  [64][64] / [128][32]
    ushort* sdbc = (ushort*)(smem + 12288);  // 2KB  [32][32]
    int tid = threadIdx.x, w = tid >> 6, lane = tid & 63;
    int quad = lane >> 4, l16 = lane & 15;
    int srow8 = lane >> 3;
    int scolx = ((lane & 7) ^ srow8) * 8;
    int cof0 = (quad ^ (l16 & 7)) * 8;
    int cof1 = ((4 + quad) ^ (l16 & 7)) * 8;

    // -------- Phase A: dbc = bwd @ Wdbc --------
    f32x4 acc[2] = {};
    for (int k0 = 0; k0 < 512; k0 += 64) {
        __syncthreads();
        {
            int r = w * 8;
            GLD16(bwd + (size_t)(bm + r + srow8) * 512 + k0 + scolx, &As[r * 64]);
        }
        #pragma unroll
        for (int s = 0; s < 2; ++s) {
            int r = w * 16 + s * 8;
            GLD16(Wdbct + (size_t)(r + srow8) * 512 + k0 + scolx, &Bs[r * 64]);
        }
        __syncthreads();
        #pragma unroll
        for (int ks = 0; ks < 2; ++ks) {
            int cof = ks ? cof1 : cof0;
            bf16x8 bfr = *(const bf16x8*)(const void*)&Bs[(w * 16 + l16) * 64 + cof];
            #pragma unroll
            for (int i = 0; i < 2; ++i) {
                bf16x8 af = *(const bf16x8*)(const void*)&As[(16 * i + l16) * 64 + cof];
                acc[i] = __builtin_amdgcn_mfma_f32_16x16x32_bf16(af, bfr, acc[i], 0, 0, 0);
            }
        }
    }
    {
        int col = w * 16 + l16;
        #pragma unroll
        for (int i = 0; i < 2; ++i) {
            int rl = 16 * i + quad * 4;
            #pragma unroll
            for (int r = 0; r < 4; ++r) {
                float v = acc[i][r];
                if (col < 32) sdbc[(rl + r) * 32 + col] = f2bf(v);
                else          BC[(size_t)(bm + rl + r) * 32 + col - 32] = v;
            }
        }
    }
    __syncthreads();
    // -------- Phase B: delta = softplus(dbc @ Wdt + b_dt) --------
    bf16x8 af2[2];
    #pragma unroll
    for (int i = 0; i < 2; ++i)
        af2[i] = *(const bf16x8*)(const void*)&sdbc[(16 * i + l16) * 32 + quad * 8];
    int srow16 = lane >> 2, sch = (lane & 3) * 8;
    for (int cn = 0; cn < 4; ++cn) {
        __syncthreads();
        #pragma unroll
        for (int s = 0; s < 2; ++s) {
            int r = w * 32 + s * 16;
            GLD16(WdtT + (size_t)(cn * 128 + r + srow16) * 32 + sch, &Bs[r * 32]);
        }
        __syncthreads();
        #pragma unroll
        for (int j = 0; j < 2; ++j) {
            bf16x8 bfr = *(const bf16x8*)(const void*)&Bs[(w * 32 + j * 16 + l16) * 32 + quad * 8];
            f32x4 a2[2] = {};
            #pragma unroll
            for (int i = 0; i < 2; ++i)
                a2[i] = __builtin_amdgcn_mfma_f32_16x16x32_bf16(af2[i], bfr, a2[i], 0, 0, 0);
            int col = cn * 128 + w * 32 + j * 16 + l16;
            float bv = b_dt[col];
            #pragma unroll
            for (int i = 0; i < 2; ++i) {
                int row = bm + 16 * i + quad * 4;
                #pragma unroll
                for (int r = 0; r < 4; ++r)
                    delta[(size_t)(row + r) * 512 + col] = f2bf(softplus_f(a2[i][r] + bv));
            }
        }
    }
    __syncthreads();
}

// scan pass1 body for one (d-half, chunk, batch) job
__device__ __forceinline__ void scan1_job(
    int d, int c, int b,
    const ushort* delta, const ushort* bwd, const float* BC,
    const float* A_log, float* hend, float* sdbuf)
{
    float A[16];
    {
        const float4* al = (const float4*)(A_log + (size_t)d * 16);
        #pragma unroll
        for (int i = 0; i < 4; ++i) {
            float4 v = al[i];
            A[4*i+0] = -__expf(v.x); A[4*i+1] = -__expf(v.y);
            A[4*i+2] = -__expf(v.z); A[4*i+3] = -__expf(v.w);
        }
    }
    float h[16];
    #pragma unroll
    for (int n = 0; n < 16; ++n) h[n] = 0.f;
    float sd = 0.f;
    size_t base = ((size_t)(b * Sdim + c * LCh)) * Ddim + d;
    const float* bcrow = BC + ((size_t)(b * Sdim + c * LCh)) * 32;
    #pragma unroll 2
    for (int i = 0; i < LCh; ++i) {
        float dlt = bf2f(delta[base + (size_t)i * Ddim]);
        float bw  = bf2f(bwd [base + (size_t)i * Ddim]);
        float4 B0 = *(const float4*)(bcrow + i * 32 + 0);
        float4 B1 = *(const float4*)(bcrow + i * 32 + 4);
        float4 B2 = *(const float4*)(bcrow + i * 32 + 8);
        float4 B3 = *(const float4*)(bcrow + i * 32 + 12);
        sd += dlt;
        float xb = dlt * bw;
        float Bv[16] = {B0.x,B0.y,B0.z,B0.w, B1.x,B1.y,B1.z,B1.w,
                        B2.x,B2.y,B2.z,B2.w, B3.x,B3.y,B3.z,B3.w};
        #pragma unroll
        for (int n = 0; n < 16; ++n)
            h[n] = fmaf(__expf(dlt * A[n]), h[n], xb * Bv[n]);
    }
    size_t cidx = ((((size_t)b * NCh + c) * Ddim) + d) * 16;
    float4* ho = (float4*)(hend + cidx);
    ho[0] = make_float4(h[0],  h[1],  h[2],  h[3]);
    ho[1] = make_float4(h[4],  h[5],  h[6],  h[7]);
    ho[2] = make_float4(h[8],  h[9],  h[10], h[11]);
    ho[3] = make_float4(h[12], h[13], h[14], h[15]);
    sdbuf[((size_t)b * NCh + c) * Ddim + d] = sd;
}

__device__ __forceinline__ void scan2_job(
    int gl, float* hend, const float* sdbuf, const float* A_log)
{
    int b = gl >> 13;
    int r = gl & 8191;
    int d = r >> 4;
    float A = -__expf(A_log[r]);
    float hin = 0.f;
    for (int c0 = 0; c0 < NCh; c0 += 8) {
        float he[8], dec[8];
        #pragma unroll
        for (int u = 0; u < 8; ++u) {
            size_t idx = (((size_t)b * NCh + c0 + u) * Ddim) * 16 + r;
            he[u]  = hend[idx];
            dec[u] = __expf(A * sdbuf[((size_t)b * NCh + c0 + u) * Ddim + d]);
        }
        #pragma unroll
        for (int u = 0; u < 8; ++u) {
            size_t idx = (((size_t)b * NCh + c0 + u) * Ddim) * 16 + r;
            hend[idx] = hin;
            hin = fmaf(dec[u], hin, he[u]);
        }
    }
}

__device__ __forceinline__ void scan3_job(
    int d, int c, int b,
    const ushort* delta, const ushort* bwd, const float* BC, const ushort* z1,
    const float* x, const float* A_log, const float* D_ssm,
    const float* hin, float* out)
{
    float A[16];
    {
        const float4* al = (const float4*)(A_log + (size_t)d * 16);
        #pragma unroll
        for (int i = 0; i < 4; ++i) {
            float4 v = al[i];
            A[4*i+0] = -__expf(v.x); A[4*i+1] = -__expf(v.y);
            A[4*i+2] = -__expf(v.z); A[4*i+3] = -__expf(v.w);
        }
    }
    float h[16];
    {
        size_t cidx = ((((size_t)b * NCh + c) * Ddim) + d) * 16;
        const float4* hi = (const float4*)(hin + cidx);
        float4 h0 = hi[0], h1 = hi[1], h2 = hi[2], h3 = hi[3];
        h[0]=h0.x; h[1]=h0.y; h[2]=h0.z; h[3]=h0.w;
        h[4]=h1.x; h[5]=h1.y; h[6]=h1.z; h[7]=h1.w;
        h[8]=h2.x; h[9]=h2.y; h[10]=h2.z; h[11]=h2.w;
        h[12]=h3.x; h[13]=h3.y; h[14]=h3.z; h[15]=h3.w;
    }
    float Dd = D_ssm[d];
    size_t base = ((size_t)(b * Sdim + c * LCh)) * Ddim + d;
    const float* bcrow = BC + ((size_t)(b * Sdim + c * LCh)) * 32;
    #pragma unroll 2
    for (int i = 0; i < LCh; ++i) {
        float dlt = bf2f(delta[base + (size_t)i * Ddim]);
        float bw  = bf2f(bwd [base + (size_t)i * Ddim]);
        float z1v = bf2f(z1  [base + (size_t)i * Ddim]);
        float xv  = x[base + (size_t)i * Ddim];
        float4 B0 = *(const float4*)(bcrow + i * 32 + 0);
        float4 B1 = *(const float4*)(bcrow + i * 32 + 4);
        float4 B2 = *(const float4*)(bcrow + i * 32 + 8);
        float4 B3 = *(const float4*)(bcrow + i * 32 + 12);
        float4 C0 = *(const float4*)(bcrow + i * 32 + 16);
        float4 C1 = *(const float4*)(bcrow + i * 32 + 20);
        float4 C2 = *(const float4*)(bcrow + i * 32 + 24);
        float4 C3 = *(const float4*)(bcrow + i * 32 + 28);
        float Bv[16] = {B0.x,B0.y,B0.z,B0.w, B1.x,B1.y,B1.z,B1.w,
                        B2.x,B2.y,B2.z,B2.w, B3.x,B3.y,B3.z,B3.w};
        float Cv[16] = {C0.x,C0.y,C0.z,C0.w, C1.x,C1.y,C1.z,C1.w,
                        C2.x,C2.y,C2.z,C2.w, C3.x,C3.y,C3.z,C3.w};
        float xb = dlt * bw;
        float y  = Dd * bw;
        #pragma unroll
        for (int n = 0; n < 16; ++n) {
            h[n] = fmaf(__expf(dlt * A[n]), h[n], xb * Bv[n]);
            y = fmaf(h[n], Cv[n], y);
        }
        float silu = z1v / (1.f + __expf(-z1v));
        out[base + (size_t)i * Ddim] = fmaf(z1v + y, silu, xv);
    }
}

// ===========================================================================
// Fused cooperative kernel: 256 blocks x 256 threads (1 block/CU always fits:
// 16KB LDS, <=512 VGPR/wave at 4 waves/CU — round 7's 512-block launch likely
// exceeded cooperative co-residency capacity at 1 block/CU occupancy).
// ===========================================================================
struct FP {
    const float *x, *gamma, *beta, *Wp, *Wb, *Wdbc, *Wdt, *bp, *bb, *bdt, *A_log, *D_ssm;
    ushort *xn, *Wpt, *Wbt, *Wdbct, *WdtT, *z1, *bwd, *delta;
    float *BC, *hend, *sdbuf, *out;
};

__global__ __launch_bounds__(256) void fused(FP P) {
    cg::grid_group g = cg::this_grid();
    __shared__ __align__(16) char smem[16384];
    int blk = blockIdx.x;
    int tid = threadIdx.x;

    // ---- P0: transposes + LayerNorm (816 jobs) ----
    #pragma unroll 1
    for (int it = 0; it < 4; ++it) {
        int job = it * 256 + blk;
        if (job < 816)
            prep_job(job, tid, smem, P.x, P.gamma, P.beta, P.Wp, P.Wb, P.Wdbc, P.Wdt,
                     P.xn, P.Wpt, P.Wbt, P.Wdbct, P.WdtT);
        __syncthreads();
    }
    g.sync();
    // ---- P1: z1 = xn @ Wp + bp (1024 tile jobs) ----
    #pragma unroll 1
    for (int it = 0; it < 4; ++it) {
        int job = it * 256 + blk;
        gemm64_tile(P.xn, P.Wpt, P.bp, P.z1, (job & 127) * 64, (job >> 7) * 64, smem);
    }
    g.sync();
    // ---- P2: bwd = z1 @ Wb + bb ----
    #pragma unroll 1
    for (int it = 0; it < 4; ++it) {
        int job = it * 256 + blk;
        gemm64_tile(P.z1, P.Wbt, P.bb, P.bwd, (job & 127) * 64, (job >> 7) * 64, smem);
    }
    g.sync();
    // ---- P3: fused dbc + delta (256 jobs) ----
    dbc_delta_tile(P.bwd, P.Wdbct, P.WdtT, P.bdt, P.BC, P.delta, blk * 32, smem);
    g.sync();
    // ---- P4: scan pass1 (512 jobs) ----
    #pragma unroll 1
    for (int it = 0; it < 2; ++it) {
        int job = it * 256 + blk;
        int d = ((job & 1) << 8) + tid;
        int c = (job >> 1) & 63;
        int b = job >> 7;
        scan1_job(d, c, b, P.delta, P.bwd, P.BC, P.A_log, P.hend, P.sdbuf);
    }
    g.sync();
    // ---- P5: scan pass2 (128 jobs) ----
    if (blk < 128)
        scan2_job(blk * 256 + tid, P.hend, P.sdbuf, P.A_log);
    g.sync();
    // ---- P6: scan pass3 + epilogue (512 jobs) ----
    #pragma unroll 1
    for (int it = 0; it < 2; ++it) {
        int job = it * 256 + blk;
        int d = ((job & 1) << 8) + tid;
        int c = (job >> 1) & 63;
        int b = job >> 7;
        scan3_job(d, c, b, P.delta, P.bwd, P.BC, P.z1, P.x, P.A_log, P.D_ssm, P.hend, P.out);
    }
}

// ===========================================================================
// Fallback kernels (round-9 proven multi-dispatch path)
// ===========================================================================
__global__ __launch_bounds__(256) void prep_all_k(
    const float* __restrict__ x, const float* __restrict__ gamma, const float* __restrict__ beta,
    const float* __restrict__ Wp, const float* __restrict__ Wb,
    const float* __restrict__ Wdbc, const float* __restrict__ Wdt,
    ushort* __restrict__ xn, ushort* __restrict__ Wpt, ushort* __restrict__ Wbt,
    ushort* __restrict__ Wdbct, ushort* __restrict__ WdtT)
{
    __shared__ __align__(16) char smem[4352];
    prep_job(blockIdx.x, threadIdx.x, smem, x, gamma, beta, Wp, Wb, Wdbc, Wdt,
             xn, Wpt, Wbt, Wdbct, WdtT);
}

__global__ __launch_bounds__(256) void gemm64_k(
    const ushort* __restrict__ A, const ushort* __restrict__ Bt,
    const float* __restrict__ bias, ushort* __restrict__ Cb)
{
    __shared__ __align__(16) char smem[16384];
    gemm64_tile(A, Bt, bias, Cb, blockIdx.x * 64, blockIdx.y * 64, smem);
}

__global__ __launch_bounds__(256) void dbc_delta_k(
    const ushort* __restrict__ bwd, const ushort* __restrict__ Wdbct,
    const ushort* __restrict__ WdtT, const float* __restrict__ b_dt,
    float* __restrict__ BC, ushort* __restrict__ delta)
{
    __shared__ __align__(16) char smem[16384];
    dbc_delta_tile(bwd, Wdbct, WdtT, b_dt, BC, delta, blockIdx.x * 32, smem);
}

__global__ __launch_bounds__(256) void scan_pass1_k(
    const ushort* __restrict__ delta, const ushort* __restrict__ bwd,
    const float* __restrict__ BC, const float* __restrict__ A_log,
    float* __restrict__ hend, float* __restrict__ sdbuf)
{
    scan1_job((blockIdx.x << 8) + threadIdx.x, blockIdx.y, blockIdx.z,
              delta, bwd, BC, A_log, hend, sdbuf);
}

__global__ __launch_bounds__(256) void scan_pass2_k(
    float* __restrict__ hend, const float* __restrict__ sdbuf,
    const float* __restrict__ A_log)
{
    scan2_job(blockIdx.x * 256 + threadIdx.x, hend, sdbuf, A_log);
}

__global__ __launch_bounds__(256) void scan_pass3_k(
    const ushort* __restrict__ delta, const ushort* __restrict__ bwd,
    const float* __restrict__ BC, const ushort* __restrict__ z1,
    const float* __restrict__ x, const float* __restrict__ A_log,
    const float* __restrict__ D_ssm, const float* __restrict__ hin,
    float* __restrict__ out)
{
    scan3_job((blockIdx.x << 8) + threadIdx.x, blockIdx.y, blockIdx.z,
              delta, bwd, BC, z1, x, A_log, D_ssm, hin, out);
}

// ---------------------------------------------------------------------------
extern "C" void kernel_launch(void* const* d_in, const int* in_sizes, int n_in,
                              void* d_out, int out_size, void* d_ws, size_t ws_size,
                              hipStream_t stream) {
    char* p = (char*)d_ws;
    FP P;
    P.x     = (const float*)d_in[0];
    P.gamma = (const float*)d_in[1];
    P.beta  = (const float*)d_in[2];
    P.Wp    = (const float*)d_in[3];
    P.bp    = (const float*)d_in[4];
    // d_in[5]=W_fwd, d_in[6]=b_fwd dead in reference (x1_ssm unused)
    P.Wb    = (const float*)d_in[7];
    P.bb    = (const float*)d_in[8];
    P.Wdbc  = (const float*)d_in[9];
    P.Wdt   = (const float*)d_in[10];
    P.bdt   = (const float*)d_in[11];
    P.A_log = (const float*)d_in[12];
    P.D_ssm = (const float*)d_in[13];
    P.out   = (float*)d_out;

    P.xn    = (ushort*)p;                        // 8 MB
    P.z1    = (ushort*)(p + (8ull  << 20));      // 8 MB
    P.bwd   = (ushort*)(p + (16ull << 20));      // 8 MB
    P.delta = (ushort*)(p + (24ull << 20));      // 8 MB
    P.BC    = (float*) (p + (33ull << 20));      // 1 MB   [8192][32]
    P.hend  = (float*) (p + (34ull << 20));      // 8 MB
    P.sdbuf = (float*) (p + (42ull << 20));      // 0.5 MB
    P.Wpt   = (ushort*)(p + (43ull << 20));      // 0.5 MB
    P.Wbt   = P.Wpt   + (size_t)512 * 512;       // 0.5 MB
    P.Wdbct = P.Wbt   + (size_t)512 * 512;       // 64 KB  [64][512]
    P.WdtT  = P.Wdbct + (size_t)64 * 512;        // 32 KB  [512][32]

    void* args[] = { &P };
    hipError_t rc = hipLaunchCooperativeKernel((void*)fused, dim3(256), dim3(256),
                                               args, 0, stream);
    if (rc != hipSuccess) {
        (void)hipGetLastError();   // clear sticky error, use proven fallback path
        prep_all_k<<<dim3(816), dim3(256), 0, stream>>>(
            P.x, P.gamma, P.beta, P.Wp, P.Wb, P.Wdbc, P.Wdt,
            P.xn, P.Wpt, P.Wbt, P.Wdbct, P.WdtT);
        gemm64_k<<<dim3(128, 8), dim3(256), 0, stream>>>(P.xn, P.Wpt, P.bp, P.z1);
        gemm64_k<<<dim3(128, 8), dim3(256), 0, stream>>>(P.z1, P.Wbt, P.bb, P.bwd);
        dbc_delta_k<<<dim3(256), dim3(256), 0, stream>>>(P.bwd, P.Wdbct, P.WdtT, P.bdt, P.BC, P.delta);
        scan_pass1_k<<<dim3(2, NCh, Bb), dim3(256), 0, stream>>>(P.delta, P.bwd, P.BC, P.A_log, P.hend, P.sdbuf);
        scan_pass2_k<<<dim3(128), dim3(256), 0, stream>>>(P.hend, P.sdbuf, P.A_log);
        scan_pass3_k<<<dim3(2, NCh, Bb), dim3(256), 0, stream>>>(P.delta, P.bwd, P.BC, P.z1, P.x, P.A_log, P.D_ssm, P.hend, P.out);
    }
}